// Round 1
// baseline (669.819 us; speedup 1.0000x reference)
//
#include <hip/hip_runtime.h>
#include <hip/hip_bf16.h>
#include <math.h>

// Problem constants
#define BATCH 16
#define G 5           // feature groups
#define CI 4          // in channels per group  (20/5)
#define CO 8          // out channels per group (40/5)
#define HW 384
#define KK 5          // padded kernel size (MAXK)
#define PADD 2

// Weight layout in workspace: [G][CI][KY][KX][CO]  (CO contiguous) = 4000 floats

__global__ void gen_weights(const float* __restrict__ alphas,
                            const float* __restrict__ scales,
                            float* __restrict__ w) {
    int idx = blockIdx.x * blockDim.x + threadIdx.x;
    if (idx >= G * CI * KK * KK) return;   // 500
    int kx = idx % 5; int r = idx / 5;
    int ky = r % 5;   r /= 5;
    int i  = r % 4;   int s = r / 4;

    float mn = 0.2f * (float)s;
    float mx = mn + 0.2f;
    float sigma = 0.5f * (mx - mn) * tanhf(scales[s]) + 0.5f * (mn + mx);
    int fs = (s < 3) ? 1 : 2;          // static half filter sizes [1,1,1,2,2]
    int p  = 2 - fs;                   // zero-pad to 5x5

    float outw[CO];
    bool valid = (ky >= p) && (ky < 5 - p) && (kx >= p) && (kx < 5 - p);
    if (!valid) {
        #pragma unroll
        for (int o = 0; o < CO; ++o) outw[o] = 0.f;
    } else {
        float inv2s2 = 1.f / (2.f * sigma * sigma);
        // unit-sum gaussian normalizer over the support
        float Gs = 0.f;
        for (int t = -fs; t <= fs; ++t) Gs += expf(-(float)(t * t) * inv2s2);
        const float sqrt2 = 1.41421356237309505f;
        float c = -1.f / (sigma * sqrt2);

        float xy = (float)(ky - p - fs);
        float xx = (float)(kx - p - fs);

        float gy = expf(-xy * xy * inv2s2) / Gs;
        float gx = expf(-xx * xx * inv2s2) / Gs;
        float uy = xy / (sigma * sqrt2);
        float ux = xx / (sigma * sqrt2);

        float dy[3], dx[3];
        dy[0] = gy;
        dy[1] = c * 2.f * uy * gy;
        dy[2] = c * c * (4.f * uy * uy - 2.f) * gy;
        dx[0] = gx;
        dx[1] = c * 2.f * ux * gx;
        dx[2] = c * c * (4.f * ux * ux - 2.f) * gx;

        // basis order: (0,0),(0,1),(0,2),(1,0),(1,1),(2,0) ; row index (k) from d[i], col (l) from d[j]
        float bas[6];
        bas[0] = dy[0] * dx[0];
        bas[1] = dy[0] * dx[1];
        bas[2] = dy[0] * dx[2];
        bas[3] = dy[1] * dx[0];
        bas[4] = dy[1] * dx[1];
        bas[5] = dy[2] * dx[0];

        #pragma unroll
        for (int o = 0; o < CO; ++o) {
            float acc = 0.f;
            #pragma unroll
            for (int n = 0; n < 6; ++n)
                acc += bas[n] * alphas[((s * 6 + n) * CI + i) * CO + o];
            outw[o] = acc;
        }
    }
    float* dst = w + ((((s * CI + i) * KK + ky) * KK + kx) * CO);
    #pragma unroll
    for (int o = 0; o < CO; ++o) dst[o] = outw[o];
}

// Tile: 32x32 outputs per block, 256 threads, each thread: 1y x 4x x 8o
#define TLE 32
#define IT 36          // input tile with halo: 32 + 2*2

typedef float v2f __attribute__((ext_vector_type(2)));

__global__ __launch_bounds__(256) void conv_kernel(const float* __restrict__ in,
                                                   const float* __restrict__ w,
                                                   float* __restrict__ out) {
    __shared__ float s_in[CI][IT][IT];   // 20736 B, row stride 36 floats = 144 B (16B aligned)
    __shared__ float s_w[CI * KK * KK * CO]; // 800 floats

    const int tileX = blockIdx.x * TLE;
    const int tileY = blockIdx.y * TLE;
    const int bz = blockIdx.z;           // b*G + g
    const int g = bz % G;
    const int b = bz / G;
    const int tid = threadIdx.x;

    // stage weights for this group
    const float* wg = w + g * (CI * KK * KK * CO);
    for (int l = tid; l < CI * KK * KK * CO; l += 256) s_w[l] = wg[l];

    // stage input tile (with zero halo at borders)
    const float* inb = in + ((size_t)b * (G * CI) + g * CI) * (HW * HW);
    for (int l = tid; l < CI * IT * IT; l += 256) {
        int c = l / (IT * IT);
        int r = l - c * (IT * IT);
        int ly = r / IT;
        int lx = r - ly * IT;
        int gy = tileY - PADD + ly;
        int gx = tileX - PADD + lx;
        float v = 0.f;
        if ((unsigned)gy < (unsigned)HW && (unsigned)gx < (unsigned)HW)
            v = inb[c * (HW * HW) + gy * HW + gx];
        s_in[c][ly][lx] = v;
    }
    __syncthreads();

    const int xc = tid & 7;        // x-chunk 0..7
    const int ty = tid >> 3;       // output row 0..31
    const int xl0 = xc * 4;        // local x of first output

    v2f acc[CO][2];
    #pragma unroll
    for (int o = 0; o < CO; ++o) { acc[o][0] = (v2f)0.f; acc[o][1] = (v2f)0.f; }

    for (int i = 0; i < CI; ++i) {
        #pragma unroll
        for (int ky = 0; ky < KK; ++ky) {
            const float* row = &s_in[i][ty + ky][xl0];
            float4 a0 = *(const float4*)(row);
            float4 a1 = *(const float4*)(row + 4);
            float  a8 = row[8];
            float iv[9] = {a0.x, a0.y, a0.z, a0.w, a1.x, a1.y, a1.z, a1.w, a8};
            const float* wrow = &s_w[(i * (KK * KK) + ky * KK) * CO];
            #pragma unroll
            for (int kx = 0; kx < KK; ++kx) {
                float4 w0 = *(const float4*)(wrow + kx * CO);
                float4 w1 = *(const float4*)(wrow + kx * CO + 4);
                v2f v01 = {iv[kx],     iv[kx + 1]};
                v2f v23 = {iv[kx + 2], iv[kx + 3]};
                float wv[8] = {w0.x, w0.y, w0.z, w0.w, w1.x, w1.y, w1.z, w1.w};
                #pragma unroll
                for (int o = 0; o < CO; ++o) {
                    v2f ws = {wv[o], wv[o]};
                    acc[o][0] += ws * v01;
                    acc[o][1] += ws * v23;
                }
            }
        }
    }

    // write 8 output channels x 4 consecutive x as float4
    const int oy = tileY + ty;
    float* outb = out + (((size_t)b * (G * CO) + g * CO) * HW + oy) * HW + tileX + xl0;
    #pragma unroll
    for (int o = 0; o < CO; ++o) {
        float4 rr;
        rr.x = acc[o][0][0];
        rr.y = acc[o][0][1];
        rr.z = acc[o][1][0];
        rr.w = acc[o][1][1];
        *(float4*)(outb + (size_t)o * (HW * HW)) = rr;
    }
}

extern "C" void kernel_launch(void* const* d_in, const int* in_sizes, int n_in,
                              void* d_out, int out_size, void* d_ws, size_t ws_size,
                              hipStream_t stream) {
    const float* data   = (const float*)d_in[0];
    const float* alphas = (const float*)d_in[1];
    const float* scales = (const float*)d_in[2];
    float* out = (float*)d_out;
    float* w   = (float*)d_ws;   // 4000 floats = 16 KB

    gen_weights<<<2, 256, 0, stream>>>(alphas, scales, w);

    dim3 grid(HW / TLE, HW / TLE, BATCH * G);   // (12, 12, 80)
    conv_kernel<<<grid, 256, 0, stream>>>(data, w, out);
}